// Round 13
// baseline (571.927 us; speedup 1.0000x reference)
//
#include <hip/hip_runtime.h>
#include <math.h>

#define NB 2
#define NN 1024
#define HH 768
#define MAXW 30
#define KTOP 409
#define BANDCAP 4096
#define BAND_TAU 2e-2f
#define FILTCAP 6144
#define GROWS 512  // 4*128 padded selected-span rows
#define WCAP 40    // max emb-row window per 128-span tile (provably <= 34)

typedef __attribute__((ext_vector_type(4))) float f32x4;
typedef __attribute__((ext_vector_type(8))) __bf16 bf16x8;
typedef __attribute__((ext_vector_type(8))) unsigned short us8;

__device__ __forceinline__ float gelu_f(float z) {
  return 0.5f * z * (1.0f + erff(z * 0.70710678118654752440f));
}
__device__ __forceinline__ unsigned f2key(float f) {
  unsigned u = __float_as_uint(f);
  return (u & 0x80000000u) ? ~u : (u | 0x80000000u);
}
__device__ __forceinline__ float key2f(unsigned k) {
  unsigned u = (k & 0x80000000u) ? (k & 0x7fffffffu) : ~k;
  return __uint_as_float(u);
}
__device__ __forceinline__ unsigned short f2bf_rn(float f) {
  unsigned u = __float_as_uint(f);
  unsigned r = u + 0x7fffu + ((u >> 16) & 1u);
  return (unsigned short)(r >> 16);
}
__device__ __forceinline__ float bf2f(unsigned short h) {
  return __uint_as_float(((unsigned)h) << 16);
}
__device__ __forceinline__ void async_copy16(const void* g, void* l) {
  __builtin_amdgcn_global_load_lds(
      (const __attribute__((address_space(1))) unsigned int*)g,
      (__attribute__((address_space(3))) unsigned int*)l, 16, 0, 0);
}

// ================= fused setup: len | R | prep_bt | prep_emb | prep_w1ab | zero =================
__global__ __launch_bounds__(256) void prep_all_kernel(
    const int* __restrict__ mask, int* __restrict__ lengths,
    const float* __restrict__ wemb, const float* __restrict__ W1,
    const float* __restrict__ b1, float* __restrict__ R,
    unsigned short* __restrict__ Bt, unsigned short* __restrict__ Btlo,
    const float* __restrict__ emb,
    unsigned short* __restrict__ Ahi, unsigned short* __restrict__ Alo,
    unsigned short* __restrict__ Bhi, unsigned short* __restrict__ Blo,
    unsigned* __restrict__ hist, int* __restrict__ bandcount, int* __restrict__ filtcount) {
  const int bx = blockIdx.x;
  const int t = threadIdx.x;
  if (bx == 0) {
    __shared__ int red[256];
    for (int b = 0; b < NB; ++b) {
      int s = 0;
      for (int i = t; i < NN; i += 256) s += mask[b * NN + i];
      red[t] = s;
      __syncthreads();
      for (int off = 128; off > 0; off >>= 1) {
        if (t < off) red[t] += red[t + off];
        __syncthreads();
      }
      if (t == 0) lengths[b] = red[0];
      __syncthreads();
    }
  } else if (bx < 31) {
    const int w = bx - 1;
    for (int h = t; h < HH; h += 256) {
      float acc = b1[h];
      for (int j = 0; j < 20; ++j)
        acc = fmaf(wemb[w * 20 + j], W1[(size_t)(3 * HH + j) * HH + h], acc);
      R[w * HH + h] = acc;
    }
  } else if (bx < 175) {
    const int l = bx - 31;
    const int ki = l % 24, hby = l / 24;
    const float* W1c = W1 + (size_t)(2 * HH) * HH;
#pragma unroll
    for (int half = 0; half < 2; ++half) {
      const int c = t + half * 256;
      const int col = c >> 2, kg = c & 3;
      us8 hv, lv;
#pragma unroll
      for (int j = 0; j < 8; ++j) {
        const int k = ki * 32 + kg * 8 + j;
        float v = W1c[(size_t)k * HH + hby * 128 + col];
        unsigned short h = f2bf_rn(v);
        hv[j] = h;
        lv[j] = f2bf_rn(v - bf2f(h));
      }
      const size_t bo = ((size_t)(hby * 24 + ki) * 512 + c) * 8;
      *(us8*)(Bt + bo) = hv;
      *(us8*)(Btlo + bo) = lv;
    }
  } else if (bx < 559) {
    const int l = bx - 175;
    const int tile = l / 24, ki = l % 24;
#pragma unroll
    for (int half = 0; half < 2; ++half) {
      const int c = t + half * 256;
      const int row = c >> 2, kgs = c & 3;
      const int kg = kgs ^ ((row >> 1) & 3);
      const float* xr = emb + (size_t)(tile * 128 + row) * HH;
      const int k0 = ki * 32 + kg * 8;
      float4 x0 = *(const float4*)(xr + k0);
      float4 x1 = *(const float4*)(xr + k0 + 4);
      const float xv[8] = {x0.x, x0.y, x0.z, x0.w, x1.x, x1.y, x1.z, x1.w};
      us8 hv, lv;
#pragma unroll
      for (int j = 0; j < 8; ++j) {
        unsigned short h = f2bf_rn(xv[j]);
        hv[j] = h;
        lv[j] = f2bf_rn(xv[j] - bf2f(h));
      }
      const size_t base = (((size_t)tile * 24 + ki) * 512 + c) * 8;
      *(us8*)(Ahi + base) = hv;
      *(us8*)(Alo + base) = lv;
    }
  } else if (bx < 847) {
    const int l = bx - 559;
    const int ki = l % 24, hby = l / 24;
#pragma unroll
    for (int half = 0; half < 2; ++half) {
      const int c = t + half * 256;
      const int col = c >> 2, kg = c & 3;
      const int gc = hby * 128 + col;
      const float* base = W1 + (gc < 768 ? (size_t)0 : (size_t)HH * HH);
      const int n = (gc < 768) ? gc : gc - 768;
      us8 hv, lv;
#pragma unroll
      for (int j = 0; j < 8; ++j) {
        const int k = ki * 32 + kg * 8 + j;
        float v = base[(size_t)k * HH + n];
        unsigned short h = f2bf_rn(v);
        hv[j] = h;
        lv[j] = f2bf_rn(v - bf2f(h));
      }
      const size_t bo = (((size_t)hby * 24 + ki) * 512 + c) * 8;
      *(us8*)(Bhi + bo) = hv;
      *(us8*)(Blo + bo) = lv;
    }
  } else {
    const int l = bx - 847;  // 0..511
    hist[l * 256 + t] = 0;
    if (l == 0 && t < NB) {
      bandcount[t] = 0;
      filtcount[t] = 0;
    }
  }
}

// ---------------- P/Q via split-bf16 MFMA ----------------
__global__ __launch_bounds__(256) void pq_mfma_kernel(
    const unsigned short* __restrict__ Ahi, const unsigned short* __restrict__ Alo,
    const unsigned short* __restrict__ Bhi, const unsigned short* __restrict__ Blo,
    float* __restrict__ P, float* __restrict__ Q) {
  __shared__ unsigned short AsmH[128 * 32], AsmL[128 * 32];
  const int tile = blockIdx.x;
  const int hby = blockIdx.y;
  const int tid = threadIdx.x;
  const int lane = tid & 63, w = tid >> 6;
  const int wm = w & 1, wn = w >> 1;
  const int lm = lane & 15, lq = lane >> 4;

  f32x4 acc[4][4];
#pragma unroll
  for (int i = 0; i < 4; ++i)
#pragma unroll
    for (int j = 0; j < 4; ++j) acc[i][j] = (f32x4){0.f, 0.f, 0.f, 0.f};

  const unsigned short* AbH = Ahi + (size_t)tile * 24 * 4096;
  const unsigned short* AbL = Alo + (size_t)tile * 24 * 4096;
  const unsigned short* BbH = Bhi + (size_t)hby * 24 * 4096;
  const unsigned short* BbL = Blo + (size_t)hby * 24 * 4096;
  const int a_off = (wm * 64 + lm) * 32 + (lq ^ ((lm >> 1) & 3)) * 8;
  const int b_off = (wn * 64 + lm) * 32 + lq * 8;

  for (int ki = 0; ki < 24; ++ki) {
    async_copy16(AbH + (size_t)ki * 4096 + tid * 8, AsmH + tid * 8);
    async_copy16(AbH + (size_t)ki * 4096 + (tid + 256) * 8, AsmH + (tid + 256) * 8);
    async_copy16(AbL + (size_t)ki * 4096 + tid * 8, AsmL + tid * 8);
    async_copy16(AbL + (size_t)ki * 4096 + (tid + 256) * 8, AsmL + (tid + 256) * 8);
    bf16x8 bh[4], bl[4];
#pragma unroll
    for (int ni = 0; ni < 4; ++ni) {
      bh[ni] = *reinterpret_cast<const bf16x8*>(BbH + (size_t)ki * 4096 + b_off + ni * 512);
      bl[ni] = *reinterpret_cast<const bf16x8*>(BbL + (size_t)ki * 4096 + b_off + ni * 512);
    }
    __syncthreads();
    bf16x8 ah[4], al[4];
#pragma unroll
    for (int mi = 0; mi < 4; ++mi) {
      ah[mi] = *reinterpret_cast<const bf16x8*>(AsmH + a_off + mi * 512);
      al[mi] = *reinterpret_cast<const bf16x8*>(AsmL + a_off + mi * 512);
    }
#pragma unroll
    for (int ni = 0; ni < 4; ++ni)
#pragma unroll
      for (int mi = 0; mi < 4; ++mi) {
        acc[mi][ni] = __builtin_amdgcn_mfma_f32_16x16x32_bf16(ah[mi], bh[ni], acc[mi][ni], 0, 0, 0);
        acc[mi][ni] = __builtin_amdgcn_mfma_f32_16x16x32_bf16(ah[mi], bl[ni], acc[mi][ni], 0, 0, 0);
        acc[mi][ni] = __builtin_amdgcn_mfma_f32_16x16x32_bf16(al[mi], bh[ni], acc[mi][ni], 0, 0, 0);
      }
    __syncthreads();
  }

  float* Obase = (hby < 6) ? P : Q;
  const int cb = ((hby < 6) ? hby : hby - 6) * 128 + wn * 64 + lm;
  const int rowb = tile * 128 + wm * 64 + lq * 4;
#pragma unroll
  for (int mi = 0; mi < 4; ++mi)
#pragma unroll
    for (int ni = 0; ni < 4; ++ni)
#pragma unroll
      for (int r = 0; r < 4; ++r)
        Obase[(size_t)(rowb + mi * 16 + r) * HH + cb + ni * 16] = acc[mi][ni][r];
}

// ---------------- MFMA scoring v8: single barrier/iter, DB Asm, reg B-prefetch ----------------
__global__ __launch_bounds__(512, 3) void score_mfma8_kernel(
    const float* __restrict__ emb, const int* __restrict__ spans,
    const unsigned short* __restrict__ Bt, const float* __restrict__ w_s,
    const float* __restrict__ P, const float* __restrict__ Q, const float* __restrict__ R,
    float* __restrict__ spart, int S) {
  __shared__ unsigned short Asm[2][128 * 32];  // 16 KB double-buffered A
  __shared__ float ew[2][WCAP * 32];           // 10 KB emb window slices
  __shared__ int ssm[128], eem[128], wwm[128];
  __shared__ float sred[128 * 4];
  __shared__ int rminS;

  const int colblk = blockIdx.x;  // 0..2 (256-col block)
  const int tile = blockIdx.y;    // 0..236
  const int b = blockIdx.z;
  const int tid = threadIdx.x;
  const int lane = tid & 63, w = tid >> 6;  // 8 waves
  const int wm = w & 1, wn = w >> 1;
  const int lm = lane & 15, lq = lane >> 4;

  if (tid < 128) {
    int g = tile * 128 + tid;
    int gg = g < S ? g : S - 1;
    int s = spans[2 * gg], e = spans[2 * gg + 1];
    ssm[tid] = s; eem[tid] = e; wwm[tid] = e - s;
  }
  __syncthreads();
  if (tid == 0) {
    int rmn = ssm[0];
    for (int i = 1; i < 128; ++i) rmn = min(rmn, ssm[i]);
    rminS = rmn;
  }
  __syncthreads();
  const int rmin = rminS;

  // staging: thread t < WCAP*8 loads one float4 of the k-slice window (coalesced)
  const int sr = tid >> 3, sc = (tid & 7) * 4;
  const int wlim = min(WCAP, NN - rmin);
  const bool stager = (tid < wlim * 8);
  const float* gsrc = emb + ((size_t)b * NN + rmin + sr) * HH + sc;
  const int ewoff = sr * 32 + sc;

  // pack: thread handles row arow, k-octet kg (swizzled)
  const int arow = tid >> 2;
  const int kgs = tid & 3;
  const int kg = kgs ^ ((arow >> 1) & 3);
  const int xo = (ssm[arow] - rmin) * 32 + kg * 8;
  const int yo = (eem[arow] - rmin) * 32 + kg * 8;
  const int aw_off = (arow * 4 + kgs) * 8;

  f32x4 acc[4][4];
#pragma unroll
  for (int i = 0; i < 4; ++i)
#pragma unroll
    for (int j = 0; j < 4; ++j) acc[i][j] = (f32x4){0.f, 0.f, 0.f, 0.f};

  const int hby = colblk * 2 + (wn >> 1);
  const unsigned short* Bb = Bt + (size_t)hby * 24 * 4096;
  const int b_off = ((wn & 1) * 64 + lm) * 32 + lq * 8;
  const int a_off = (wm * 64 + lm) * 32 + (lq ^ ((lm >> 1) & 3)) * 8;

  // prologue: slices 0,1 -> ew; pack A(0) -> Asm[0]; breg = B(0); reg = slice 2
  if (stager) {
    float4 r0 = *(const float4*)gsrc;
    float4 r1 = *(const float4*)(gsrc + 32);
    *(float4*)(&ew[0][ewoff]) = r0;
    *(float4*)(&ew[1][ewoff]) = r1;
  }
  __syncthreads();
  {
    float4 x0 = *(const float4*)(&ew[0][xo]);
    float4 x1 = *(const float4*)(&ew[0][xo + 4]);
    float4 y0 = *(const float4*)(&ew[0][yo]);
    float4 y1 = *(const float4*)(&ew[0][yo + 4]);
    us8 v;
    v[0] = f2bf_rn(x0.x * y0.x); v[1] = f2bf_rn(x0.y * y0.y);
    v[2] = f2bf_rn(x0.z * y0.z); v[3] = f2bf_rn(x0.w * y0.w);
    v[4] = f2bf_rn(x1.x * y1.x); v[5] = f2bf_rn(x1.y * y1.y);
    v[6] = f2bf_rn(x1.z * y1.z); v[7] = f2bf_rn(x1.w * y1.w);
    *(us8*)(&Asm[0][aw_off]) = v;
  }
  bf16x8 breg[4];
#pragma unroll
  for (int ni = 0; ni < 4; ++ni)
    breg[ni] = *reinterpret_cast<const bf16x8*>(Bb + b_off + ni * 512);
  float4 reg = make_float4(0.f, 0.f, 0.f, 0.f);
  if (stager) reg = *(const float4*)(gsrc + 2 * 32);
  __syncthreads();

  int cur = 0;
  for (int ki = 0; ki < 24; ++ki) {
    // A-fragments for this iter (issued first; latency hidden under pack)
    bf16x8 afr[4];
#pragma unroll
    for (int mi = 0; mi < 4; ++mi)
      afr[mi] = *reinterpret_cast<const bf16x8*>(&Asm[cur][a_off + mi * 512]);
    // register-prefetch B(ki+1) — stays in flight across the barrier
    bf16x8 bnext[4];
    if (ki < 23) {
#pragma unroll
      for (int ni = 0; ni < 4; ++ni)
        bnext[ni] = *reinterpret_cast<const bf16x8*>(Bb + (size_t)(ki + 1) * 4096 + b_off + ni * 512);
    }
    // pack A(ki+1) into Asm[cur^1]
    if (ki < 23) {
      const float* e1 = ew[(ki + 1) & 1];
      float4 x0 = *(const float4*)(&e1[xo]);
      float4 x1 = *(const float4*)(&e1[xo + 4]);
      float4 y0 = *(const float4*)(&e1[yo]);
      float4 y1 = *(const float4*)(&e1[yo + 4]);
      us8 v;
      v[0] = f2bf_rn(x0.x * y0.x); v[1] = f2bf_rn(x0.y * y0.y);
      v[2] = f2bf_rn(x0.z * y0.z); v[3] = f2bf_rn(x0.w * y0.w);
      v[4] = f2bf_rn(x1.x * y1.x); v[5] = f2bf_rn(x1.y * y1.y);
      v[6] = f2bf_rn(x1.z * y1.z); v[7] = f2bf_rn(x1.w * y1.w);
      *(us8*)(&Asm[cur ^ 1][aw_off]) = v;
    }
    // ew slice pipeline: store slice(ki+2) into ew[ki&1]; prefetch slice(ki+3)
    if (stager && ki + 2 < 24) *(float4*)(&ew[ki & 1][ewoff]) = reg;
    if (stager && ki + 3 < 24) reg = *(const float4*)(gsrc + (size_t)(ki + 3) * 32);
    // MFMA with pre-landed B(ki)
#pragma unroll
    for (int ni = 0; ni < 4; ++ni)
#pragma unroll
      for (int mi = 0; mi < 4; ++mi)
        acc[mi][ni] = __builtin_amdgcn_mfma_f32_16x16x32_bf16(afr[mi], breg[ni], acc[mi][ni], 0, 0, 0);
    if (ki < 23) {
#pragma unroll
      for (int ni = 0; ni < 4; ++ni) breg[ni] = bnext[ni];
    }
    __syncthreads();
    cur ^= 1;
  }

  const int cbase = colblk * 256 + wn * 64 + lm;
  float wsv[4];
#pragma unroll
  for (int ni = 0; ni < 4; ++ni) wsv[ni] = w_s[cbase + ni * 16];

#pragma unroll
  for (int mi = 0; mi < 4; ++mi) {
#pragma unroll
    for (int r = 0; r < 4; ++r) {
      const int rowl = wm * 64 + mi * 16 + lq * 4 + r;
      const int s = ssm[rowl], e = eem[rowl], wd = wwm[rowl];
      const float* Pp = P + ((size_t)b * NN + s) * HH + cbase;
      const float* Qp = Q + ((size_t)b * NN + e) * HH + cbase;
      const float* Rp = R + (size_t)wd * HH + cbase;
      float psum = 0.f;
#pragma unroll
      for (int ni = 0; ni < 4; ++ni) {
        float z = acc[mi][ni][r] + Pp[ni * 16] + Qp[ni * 16] + Rp[ni * 16];
        psum = fmaf(gelu_f(z), wsv[ni], psum);
      }
      psum += __shfl_xor(psum, 1);
      psum += __shfl_xor(psum, 2);
      psum += __shfl_xor(psum, 4);
      psum += __shfl_xor(psum, 8);
      if (lm == 0) sred[rowl * 4 + wn] = psum;
    }
  }
  __syncthreads();
  if (tid < 128) {
    int g = tile * 128 + tid;
    if (g < S)
      spart[(size_t)colblk * ((size_t)NB * S) + (size_t)b * S + g] =
          sred[tid * 4] + sred[tid * 4 + 1] + sred[tid * 4 + 2] + sred[tid * 4 + 3];
  }
}

// ---------------- fused combine + 16-bit histogram ----------------
__global__ void combine_hist_kernel(const float* __restrict__ sp, const int* __restrict__ spans,
                                    const float* __restrict__ b_s, const int* __restrict__ lengths,
                                    float* __restrict__ scores, unsigned* __restrict__ hist,
                                    int S) {
  int idx = blockIdx.x * 256 + threadIdx.x;
  if (idx >= NB * S) return;
  int b = idx / S, i = idx - b * S;
  size_t st = (size_t)NB * S;
  float v = b_s[0];
#pragma unroll
  for (int j = 0; j < 3; ++j) v += sp[j * st + idx];
  if (spans[2 * i + 1] >= lengths[b]) v += -1000000.0f;
  scores[idx] = v;
  unsigned key = f2key(v) >> 16;
  atomicAdd(&hist[(size_t)b * 65536 + key], 1u);
}

// ---------------- scan bins descending -> kth bin lower edge ----------------
__global__ __launch_bounds__(1024) void scan16_kernel(const unsigned* __restrict__ hist,
                                                      const int* __restrict__ kptr,
                                                      float* __restrict__ pivotf) {
  const int b = blockIdx.x;
  const unsigned* hb = hist + (size_t)b * 65536;
  const int tid = threadIdx.x;
  const unsigned k = (unsigned)kptr[0];
  __shared__ unsigned acc[1024];
  unsigned s = 0;
  for (int j = 0; j < 64; ++j) s += hb[tid * 64 + j];
  const unsigned mysum = s;
  acc[tid] = s;
  __syncthreads();
  for (int off = 1; off < 1024; off <<= 1) {
    unsigned v = (tid + off < 1024) ? acc[tid + off] : 0u;
    __syncthreads();
    acc[tid] += v;
    __syncthreads();
  }
  const unsigned above = acc[tid] - mysum;
  if (above < k && acc[tid] >= k) {
    unsigned cum = above;
    int binf = tid * 64;
    for (int j = 63; j >= 0; --j) {
      unsigned c = hb[tid * 64 + j];
      if (cum + c >= k) { binf = tid * 64 + j; break; }
      cum += c;
    }
    pivotf[b] = key2f(((unsigned)binf) << 16);
  }
}

// ---------------- band collect (approx scores near pivot) ----------------
__global__ void band_kernel(const float* __restrict__ scores, const float* __restrict__ pivotf,
                            int* __restrict__ bandcount, int* __restrict__ bandlist, int S) {
  int idx = blockIdx.x * 256 + threadIdx.x;
  if (idx >= NB * S) return;
  int b = idx / S, i = idx - b * S;
  if (fabsf(scores[idx] - pivotf[b]) <= BAND_TAU) {
    int slot = atomicAdd(&bandcount[b], 1);
    if (slot < BANDCAP) bandlist[b * BANDCAP + slot] = i;
  }
}

// ---------------- exact fp32 rescore of band spans ----------------
__global__ __launch_bounds__(256) void rescore_kernel(
    const float* __restrict__ emb, const int* __restrict__ spans,
    const float* __restrict__ W1, const float* __restrict__ w_s,
    const float* __restrict__ b_s, const int* __restrict__ lengths,
    const float* __restrict__ P, const float* __restrict__ Q, const float* __restrict__ R,
    const int* __restrict__ bandcount, const int* __restrict__ bandlist,
    float* __restrict__ scores, int S) {
  const int b = blockIdx.y;
  int cnt = bandcount[b];
  if (cnt > BANDCAP) cnt = BANDCAP;
  if ((int)blockIdx.x >= cnt) return;
  const int i = bandlist[b * BANDCAP + blockIdx.x];
  const int s = spans[2 * i], e = spans[2 * i + 1], wd = e - s;
  const int tid = threadIdx.x;
  __shared__ float prod[HH];
  __shared__ float red[256];
  for (int c = tid; c < HH; c += 256)
    prod[c] = emb[((size_t)b * NN + s) * HH + c] * emb[((size_t)b * NN + e) * HH + c];
  __syncthreads();
  const float* W1c = W1 + (size_t)(2 * HH) * HH;
  float psum = 0.f;
  for (int c0 = 0; c0 < HH; c0 += 256) {
    const int c = c0 + tid;
    float a = P[((size_t)b * NN + s) * HH + c] + Q[((size_t)b * NN + e) * HH + c] + R[(size_t)wd * HH + c];
    for (int k = 0; k < HH; ++k) a = fmaf(prod[k], W1c[(size_t)k * HH + c], a);
    psum = fmaf(gelu_f(a), w_s[c], psum);
  }
  red[tid] = psum;
  __syncthreads();
  for (int off = 128; off > 0; off >>= 1) {
    if (tid < off) red[tid] += red[tid + off];
    __syncthreads();
  }
  if (tid == 0) {
    float v = red[0] + b_s[0];
    if (e >= lengths[b]) v += -1000000.0f;
    scores[(size_t)b * S + i] = v;
  }
}

// ---------------- parallel candidate filter (final scores) ----------------
__global__ void filt_kernel(const float* __restrict__ scores, const float* __restrict__ pivotf,
                            int* __restrict__ filtcount, int* __restrict__ filtlist, int S) {
  int idx = blockIdx.x * 256 + threadIdx.x;
  if (idx >= NB * S) return;
  int b = idx / S, i = idx - b * S;
  if (scores[idx] > pivotf[b] - 0.01f) {
    int slot = atomicAdd(&filtcount[b], 1);
    if (slot < FILTCAP) filtlist[b * FILTCAP + slot] = i;
  }
}

// ---------------- exact top-k on candidate set ----------------
__global__ __launch_bounds__(1024) void sel_kernel(
    const float* __restrict__ scores, const int* __restrict__ spans,
    const int* __restrict__ kptr, const int* __restrict__ filtcount,
    const int* __restrict__ filtlist,
    float* __restrict__ out_spans, int* __restrict__ sel, int S) {
  const int b = blockIdx.x;
  const int tid = threadIdx.x;
  const int k = kptr[0];
  __shared__ unsigned keys[FILTCAP];
  __shared__ int idxs[FILTCAP];
  __shared__ unsigned hist[256];
  __shared__ unsigned sh_prefix;
  __shared__ int sh_remaining;
  __shared__ int selcnt;
  __shared__ int slist[512];

  int M = filtcount[b];
  if (M > FILTCAP) M = FILTCAP;
  for (int i = tid; i < M; i += 1024) {
    int gi = filtlist[b * FILTCAP + i];
    idxs[i] = gi;
    keys[i] = f2key(scores[(size_t)b * S + gi]);
  }
  if (tid == 0) selcnt = 0;
  __syncthreads();

  unsigned prefix = 0;
  int remaining = k;
  for (int round = 0; round < 4; ++round) {
    const int shift = 24 - 8 * round;
    if (tid < 256) hist[tid] = 0;
    __syncthreads();
    for (int i = tid; i < M; i += 1024) {
      unsigned key = keys[i];
      if (round == 0 || (key >> (shift + 8)) == prefix)
        atomicAdd(&hist[(key >> shift) & 255u], 1u);
    }
    __syncthreads();
    if (tid == 0) {
      int cum = 0;
      for (int bin = 255; bin >= 0; --bin) {
        int c = (int)hist[bin];
        if (cum + c >= remaining) {
          sh_prefix = (prefix << 8) | (unsigned)bin;
          sh_remaining = remaining - cum;
          break;
        }
        cum += c;
      }
    }
    __syncthreads();
    prefix = sh_prefix;
    remaining = sh_remaining;
    __syncthreads();
  }
  const unsigned pk = prefix;
  const int m_eq = remaining;

  for (int i = tid; i < M; i += 1024) {
    unsigned key = keys[i];
    bool pick = false;
    if (key > pk) {
      pick = true;
    } else if (key == pk) {
      int r = 0;
      const int myidx = idxs[i];
      for (int j = 0; j < M; ++j)
        if (keys[j] == pk && idxs[j] < myidx) ++r;
      pick = (r < m_eq);
    }
    if (pick) {
      int p = atomicAdd(&selcnt, 1);
      if (p < 512) slist[p] = idxs[i];
    }
  }
  __syncthreads();

  for (int i = tid; i < k; i += 1024) {
    const int my = slist[i];
    int r = 0;
    for (int j = 0; j < k; ++j) r += (slist[j] < my);
    sel[b * KTOP + r] = my;
    out_spans[(b * KTOP + r) * 2 + 0] = (float)spans[2 * my];
    out_spans[(b * KTOP + r) * 2 + 1] = (float)spans[2 * my + 1];
  }
}

// ---------------- prep gather A: hi/lo bf16(x*y) for selected spans ----------------
__global__ __launch_bounds__(256) void prep_ga_kernel(
    const float* __restrict__ emb, const int* __restrict__ spans,
    const int* __restrict__ sel, unsigned short* __restrict__ GAhi,
    unsigned short* __restrict__ GAlo) {
  const int bx = blockIdx.x;     // 0..95: tile*24 + ki
  const int tile = bx / 24, ki = bx - tile * 24;
  const int b = blockIdx.y;
  const int t = threadIdx.x;
#pragma unroll
  for (int half = 0; half < 2; ++half) {
    const int c = t + half * 256;
    const int row = c >> 2, kgs = c & 3;
    const int kg = kgs ^ ((row >> 1) & 3);
    int j = tile * 128 + row;
    if (j >= KTOP) j = KTOP - 1;
    const int i = sel[b * KTOP + j];
    const int s = spans[2 * i], e = spans[2 * i + 1];
    const float* xr = emb + ((size_t)b * NN + s) * HH;
    const float* yr = emb + ((size_t)b * NN + e) * HH;
    const int k0 = ki * 32 + kg * 8;
    float4 x0 = *(const float4*)(xr + k0);
    float4 x1 = *(const float4*)(xr + k0 + 4);
    float4 y0 = *(const float4*)(yr + k0);
    float4 y1 = *(const float4*)(yr + k0 + 4);
    const float pv[8] = {x0.x * y0.x, x0.y * y0.y, x0.z * y0.z, x0.w * y0.w,
                         x1.x * y1.x, x1.y * y1.y, x1.z * y1.z, x1.w * y1.w};
    us8 hv, lv;
#pragma unroll
    for (int q = 0; q < 8; ++q) {
      unsigned short h = f2bf_rn(pv[q]);
      hv[q] = h;
      lv[q] = f2bf_rn(pv[q] - bf2f(h));
    }
    const size_t base = (((size_t)(b * 4 + tile) * 24 + ki) * 512 + c) * 8;
    *(us8*)(GAhi + base) = hv;
    *(us8*)(GAlo + base) = lv;
  }
}

// ---------------- gather via split-bf16 MFMA: h embeddings + score partials ----------------
__global__ __launch_bounds__(256) void gather_mfma_kernel(
    const int* __restrict__ spans, const int* __restrict__ sel,
    const unsigned short* __restrict__ GAhi, const unsigned short* __restrict__ GAlo,
    const unsigned short* __restrict__ Bt, const unsigned short* __restrict__ Btlo,
    const float* __restrict__ w_s,
    const float* __restrict__ P, const float* __restrict__ Q, const float* __restrict__ R,
    float* __restrict__ outh, float* __restrict__ spartg) {
  __shared__ unsigned short AsmH[128 * 32], AsmL[128 * 32];
  __shared__ int ssm[128], eem[128], wwm[128], vvm[128];
  __shared__ float sred[128 * 2];
  const int tile = blockIdx.x;  // 0..3
  const int hby = blockIdx.y;   // 0..5
  const int b = blockIdx.z;
  const int tid = threadIdx.x;
  const int lane = tid & 63, w = tid >> 6;
  const int wm = w & 1, wn = w >> 1;
  const int lm = lane & 15, lq = lane >> 4;

  if (tid < 128) {
    int j = tile * 128 + tid;
    int valid = (j < KTOP) ? 1 : 0;
    int jj = valid ? j : KTOP - 1;
    int i = sel[b * KTOP + jj];
    ssm[tid] = spans[2 * i];
    eem[tid] = spans[2 * i + 1];
    wwm[tid] = eem[tid] - ssm[tid];
    vvm[tid] = valid;
  }

  f32x4 acc[4][4];
#pragma unroll
  for (int i = 0; i < 4; ++i)
#pragma unroll
    for (int j = 0; j < 4; ++j) acc[i][j] = (f32x4){0.f, 0.f, 0.f, 0.f};

  const unsigned short* AbH = GAhi + (size_t)(b * 4 + tile) * 24 * 4096;
  const unsigned short* AbL = GAlo + (size_t)(b * 4 + tile) * 24 * 4096;
  const unsigned short* BbH = Bt + (size_t)hby * 24 * 4096;
  const unsigned short* BbL = Btlo + (size_t)hby * 24 * 4096;
  const int a_off = (wm * 64 + lm) * 32 + (lq ^ ((lm >> 1) & 3)) * 8;
  const int b_off = (wn * 64 + lm) * 32 + lq * 8;

  for (int ki = 0; ki < 24; ++ki) {
    async_copy16(AbH + (size_t)ki * 4096 + tid * 8, AsmH + tid * 8);
    async_copy16(AbH + (size_t)ki * 4096 + (tid + 256) * 8, AsmH + (tid + 256) * 8);
    async_copy16(AbL + (size_t)ki * 4096 + tid * 8, AsmL + tid * 8);
    async_copy16(AbL + (size_t)ki * 4096 + (tid + 256) * 8, AsmL + (tid + 256) * 8);
    bf16x8 bh[4], bl[4];
#pragma unroll
    for (int ni = 0; ni < 4; ++ni) {
      bh[ni] = *reinterpret_cast<const bf16x8*>(BbH + (size_t)ki * 4096 + b_off + ni * 512);
      bl[ni] = *reinterpret_cast<const bf16x8*>(BbL + (size_t)ki * 4096 + b_off + ni * 512);
    }
    __syncthreads();
    bf16x8 ah[4], al[4];
#pragma unroll
    for (int mi = 0; mi < 4; ++mi) {
      ah[mi] = *reinterpret_cast<const bf16x8*>(AsmH + a_off + mi * 512);
      al[mi] = *reinterpret_cast<const bf16x8*>(AsmL + a_off + mi * 512);
    }
#pragma unroll
    for (int ni = 0; ni < 4; ++ni)
#pragma unroll
      for (int mi = 0; mi < 4; ++mi) {
        acc[mi][ni] = __builtin_amdgcn_mfma_f32_16x16x32_bf16(ah[mi], bh[ni], acc[mi][ni], 0, 0, 0);
        acc[mi][ni] = __builtin_amdgcn_mfma_f32_16x16x32_bf16(ah[mi], bl[ni], acc[mi][ni], 0, 0, 0);
        acc[mi][ni] = __builtin_amdgcn_mfma_f32_16x16x32_bf16(al[mi], bh[ni], acc[mi][ni], 0, 0, 0);
      }
    __syncthreads();
  }

  const int hbg = hby * 128;
  float wsv[4];
#pragma unroll
  for (int ni = 0; ni < 4; ++ni) wsv[ni] = w_s[hbg + wn * 64 + ni * 16 + lm];

#pragma unroll
  for (int mi = 0; mi < 4; ++mi) {
#pragma unroll
    for (int r = 0; r < 4; ++r) {
      const int rowl = wm * 64 + mi * 16 + lq * 4 + r;
      const int s = ssm[rowl], e = eem[rowl], wd = wwm[rowl];
      const float* Pp = P + ((size_t)b * NN + s) * HH + hbg + wn * 64 + lm;
      const float* Qp = Q + ((size_t)b * NN + e) * HH + hbg + wn * 64 + lm;
      const float* Rp = R + (size_t)wd * HH + hbg + wn * 64 + lm;
      float psum = 0.f;
      const int j = tile * 128 + rowl;
      float* op = outh + (size_t)(b * KTOP + j) * HH + hbg + wn * 64 + lm;
#pragma unroll
      for (int ni = 0; ni < 4; ++ni) {
        float z = acc[mi][ni][r] + Pp[ni * 16] + Qp[ni * 16] + Rp[ni * 16];
        float gl = gelu_f(z);
        if (vvm[rowl]) op[ni * 16] = gl;
        psum = fmaf(gl, wsv[ni], psum);
      }
      psum += __shfl_xor(psum, 1);
      psum += __shfl_xor(psum, 2);
      psum += __shfl_xor(psum, 4);
      psum += __shfl_xor(psum, 8);
      if (lm == 0) sred[rowl * 2 + wn] = psum;
    }
  }
  __syncthreads();
  if (tid < 128)
    spartg[(size_t)hby * (NB * GROWS) + b * GROWS + tile * 128 + tid] =
        sred[tid * 2] + sred[tid * 2 + 1];
}

// ---------------- final scores for selected spans ----------------
__global__ void score_fin_kernel(const float* __restrict__ spartg, const int* __restrict__ sel,
                                 const int* __restrict__ spans, const float* __restrict__ b_s,
                                 const int* __restrict__ lengths, float* __restrict__ out_scores) {
  int idx = blockIdx.x * 256 + threadIdx.x;
  if (idx >= NB * KTOP) return;
  int b = idx / KTOP, j = idx - b * KTOP;
  float v = b_s[0];
#pragma unroll
  for (int hby = 0; hby < 6; ++hby)
    v += spartg[(size_t)hby * (NB * GROWS) + b * GROWS + j];
  int i = sel[idx];
  if (spans[2 * i + 1] >= lengths[b]) v += -1000000.0f;
  out_scores[idx] = v;
}

extern "C" void kernel_launch(void* const* d_in, const int* in_sizes, int n_in,
                              void* d_out, int out_size, void* d_ws, size_t ws_size,
                              hipStream_t stream) {
  const float* emb = (const float*)d_in[0];
  const int* mask = (const int*)d_in[1];
  const int* spans = (const int*)d_in[2];
  const float* wemb = (const float*)d_in[3];
  const float* W1 = (const float*)d_in[4];
  const float* b1 = (const float*)d_in[5];
  const float* w_s = (const float*)d_in[6];
  const float* b_s = (const float*)d_in[7];
  const int* kptr = (const int*)d_in[8];
  const int S = in_sizes[2] / 2;  // 30285
  float* out = (float*)d_out;

  char* wp = (char*)d_ws;
  auto take = [&](size_t bytes) {
    char* p = wp;
    wp += (bytes + 63) & ~(size_t)63;
    return p;
  };
  float* Pb = (float*)take((size_t)NB * NN * HH * 4);
  float* Qb = (float*)take((size_t)NB * NN * HH * 4);
  float* Rb = (float*)take((size_t)MAXW * HH * 4);
  float* spart = (float*)take(3 * (size_t)NB * S * 4);
  float* scoresb = (float*)take((size_t)NB * S * 4);
  float* spartg = (float*)take(6 * (size_t)NB * GROWS * 4);
  float* pivotf = (float*)take(NB * 4);
  unsigned short* AimgHi = (unsigned short*)take((size_t)16 * 24 * 4096 * 2);
  unsigned short* AimgLo = (unsigned short*)take((size_t)16 * 24 * 4096 * 2);
  unsigned short* BimgHi = (unsigned short*)take((size_t)12 * 24 * 4096 * 2);
  unsigned short* BimgLo = (unsigned short*)take((size_t)12 * 24 * 4096 * 2);
  unsigned short* Bt = (unsigned short*)take((size_t)6 * 24 * 4096 * 2);
  unsigned short* Btlo = (unsigned short*)take((size_t)6 * 24 * 4096 * 2);
  unsigned short* GAhi = (unsigned short*)take((size_t)NB * 4 * 24 * 4096 * 2);
  unsigned short* GAlo = (unsigned short*)take((size_t)NB * 4 * 24 * 4096 * 2);
  unsigned* hist16b = (unsigned*)take((size_t)NB * 65536 * 4);
  int* selb = (int*)take(NB * KTOP * 4);
  int* lengthsb = (int*)take(NB * 4);
  int* bandcount = (int*)take(NB * 4);
  int* bandlist = (int*)take((size_t)NB * BANDCAP * 4);
  int* filtcount = (int*)take(NB * 4);
  int* filtlist = (int*)take((size_t)NB * FILTCAP * 4);

  const size_t OFF1 = (size_t)NB * KTOP * HH;    // embs
  const size_t OFF2 = OFF1 + (size_t)NB * KTOP;  // scores | spans

  const int tiles = (S + 127) / 128;  // 237

  prep_all_kernel<<<dim3(1359), dim3(256), 0, stream>>>(
      mask, lengthsb, wemb, W1, b1, Rb, Bt, Btlo, emb, AimgHi, AimgLo, BimgHi, BimgLo,
      hist16b, bandcount, filtcount);
  pq_mfma_kernel<<<dim3(16, 12), dim3(256), 0, stream>>>(AimgHi, AimgLo, BimgHi, BimgLo, Pb, Qb);
  score_mfma8_kernel<<<dim3(3, tiles, NB), dim3(512), 0, stream>>>(
      emb, spans, Bt, w_s, Pb, Qb, Rb, spart, S);
  combine_hist_kernel<<<dim3((NB * S + 255) / 256), dim3(256), 0, stream>>>(
      spart, spans, b_s, lengthsb, scoresb, hist16b, S);
  scan16_kernel<<<dim3(NB), dim3(1024), 0, stream>>>(hist16b, kptr, pivotf);
  band_kernel<<<dim3((NB * S + 255) / 256), dim3(256), 0, stream>>>(
      scoresb, pivotf, bandcount, bandlist, S);
  rescore_kernel<<<dim3(BANDCAP, NB), dim3(256), 0, stream>>>(
      emb, spans, W1, w_s, b_s, lengthsb, Pb, Qb, Rb, bandcount, bandlist, scoresb, S);
  filt_kernel<<<dim3((NB * S + 255) / 256), dim3(256), 0, stream>>>(
      scoresb, pivotf, filtcount, filtlist, S);
  sel_kernel<<<dim3(NB), dim3(1024), 0, stream>>>(
      scoresb, spans, kptr, filtcount, filtlist, out + OFF2, selb, S);
  prep_ga_kernel<<<dim3(96, NB), dim3(256), 0, stream>>>(emb, spans, selb, GAhi, GAlo);
  gather_mfma_kernel<<<dim3(4, 6, NB), dim3(256), 0, stream>>>(
      spans, selb, GAhi, GAlo, Bt, Btlo, w_s, Pb, Qb, Rb, out, spartg);
  score_fin_kernel<<<dim3((NB * KTOP + 255) / 256), dim3(256), 0, stream>>>(
      spartg, selb, spans, b_s, lengthsb, out + OFF1);
}

// Round 14
// 534.478 us; speedup vs baseline: 1.0701x; 1.0701x over previous
//
#include <hip/hip_runtime.h>
#include <math.h>

#define NB 2
#define NN 1024
#define HH 768
#define MAXW 30
#define KTOP 409
#define BANDCAP 4096
#define BAND_TAU 2e-2f
#define FILTCAP 6144
#define GROWS 512  // 4*128 padded selected-span rows
#define WCAP 40    // max emb-row window per 128-span tile (provably <= 34)

typedef __attribute__((ext_vector_type(4))) float f32x4;
typedef __attribute__((ext_vector_type(8))) __bf16 bf16x8;
typedef __attribute__((ext_vector_type(8))) unsigned short us8;

__device__ __forceinline__ float gelu_f(float z) {
  return 0.5f * z * (1.0f + erff(z * 0.70710678118654752440f));
}
__device__ __forceinline__ unsigned f2key(float f) {
  unsigned u = __float_as_uint(f);
  return (u & 0x80000000u) ? ~u : (u | 0x80000000u);
}
__device__ __forceinline__ float key2f(unsigned k) {
  unsigned u = (k & 0x80000000u) ? (k & 0x7fffffffu) : ~k;
  return __uint_as_float(u);
}
__device__ __forceinline__ unsigned short f2bf_rn(float f) {
  unsigned u = __float_as_uint(f);
  unsigned r = u + 0x7fffu + ((u >> 16) & 1u);
  return (unsigned short)(r >> 16);
}
__device__ __forceinline__ float bf2f(unsigned short h) {
  return __uint_as_float(((unsigned)h) << 16);
}
__device__ __forceinline__ void async_copy16(const void* g, void* l) {
  __builtin_amdgcn_global_load_lds(
      (const __attribute__((address_space(1))) unsigned int*)g,
      (__attribute__((address_space(3))) unsigned int*)l, 16, 0, 0);
}

// ================= fused setup: len | R | prep_bt | prep_emb | prep_w1ab | zero =================
__global__ __launch_bounds__(256) void prep_all_kernel(
    const int* __restrict__ mask, int* __restrict__ lengths,
    const float* __restrict__ wemb, const float* __restrict__ W1,
    const float* __restrict__ b1, float* __restrict__ R,
    unsigned short* __restrict__ Bt, unsigned short* __restrict__ Btlo,
    const float* __restrict__ emb,
    unsigned short* __restrict__ Ahi, unsigned short* __restrict__ Alo,
    unsigned short* __restrict__ Bhi, unsigned short* __restrict__ Blo,
    unsigned* __restrict__ hist, int* __restrict__ bandcount, int* __restrict__ filtcount) {
  const int bx = blockIdx.x;
  const int t = threadIdx.x;
  if (bx == 0) {
    __shared__ int red[256];
    for (int b = 0; b < NB; ++b) {
      int s = 0;
      for (int i = t; i < NN; i += 256) s += mask[b * NN + i];
      red[t] = s;
      __syncthreads();
      for (int off = 128; off > 0; off >>= 1) {
        if (t < off) red[t] += red[t + off];
        __syncthreads();
      }
      if (t == 0) lengths[b] = red[0];
      __syncthreads();
    }
  } else if (bx < 31) {
    const int w = bx - 1;
    for (int h = t; h < HH; h += 256) {
      float acc = b1[h];
      for (int j = 0; j < 20; ++j)
        acc = fmaf(wemb[w * 20 + j], W1[(size_t)(3 * HH + j) * HH + h], acc);
      R[w * HH + h] = acc;
    }
  } else if (bx < 175) {
    const int l = bx - 31;
    const int ki = l % 24, hby = l / 24;
    const float* W1c = W1 + (size_t)(2 * HH) * HH;
#pragma unroll
    for (int half = 0; half < 2; ++half) {
      const int c = t + half * 256;
      const int col = c >> 2, kg = c & 3;
      us8 hv, lv;
#pragma unroll
      for (int j = 0; j < 8; ++j) {
        const int k = ki * 32 + kg * 8 + j;
        float v = W1c[(size_t)k * HH + hby * 128 + col];
        unsigned short h = f2bf_rn(v);
        hv[j] = h;
        lv[j] = f2bf_rn(v - bf2f(h));
      }
      const size_t bo = ((size_t)(hby * 24 + ki) * 512 + c) * 8;
      *(us8*)(Bt + bo) = hv;
      *(us8*)(Btlo + bo) = lv;
    }
  } else if (bx < 559) {
    const int l = bx - 175;
    const int tile = l / 24, ki = l % 24;
#pragma unroll
    for (int half = 0; half < 2; ++half) {
      const int c = t + half * 256;
      const int row = c >> 2, kgs = c & 3;
      const int kg = kgs ^ ((row >> 1) & 3);
      const float* xr = emb + (size_t)(tile * 128 + row) * HH;
      const int k0 = ki * 32 + kg * 8;
      float4 x0 = *(const float4*)(xr + k0);
      float4 x1 = *(const float4*)(xr + k0 + 4);
      const float xv[8] = {x0.x, x0.y, x0.z, x0.w, x1.x, x1.y, x1.z, x1.w};
      us8 hv, lv;
#pragma unroll
      for (int j = 0; j < 8; ++j) {
        unsigned short h = f2bf_rn(xv[j]);
        hv[j] = h;
        lv[j] = f2bf_rn(xv[j] - bf2f(h));
      }
      const size_t base = (((size_t)tile * 24 + ki) * 512 + c) * 8;
      *(us8*)(Ahi + base) = hv;
      *(us8*)(Alo + base) = lv;
    }
  } else if (bx < 847) {
    const int l = bx - 559;
    const int ki = l % 24, hby = l / 24;
#pragma unroll
    for (int half = 0; half < 2; ++half) {
      const int c = t + half * 256;
      const int col = c >> 2, kg = c & 3;
      const int gc = hby * 128 + col;
      const float* base = W1 + (gc < 768 ? (size_t)0 : (size_t)HH * HH);
      const int n = (gc < 768) ? gc : gc - 768;
      us8 hv, lv;
#pragma unroll
      for (int j = 0; j < 8; ++j) {
        const int k = ki * 32 + kg * 8 + j;
        float v = base[(size_t)k * HH + n];
        unsigned short h = f2bf_rn(v);
        hv[j] = h;
        lv[j] = f2bf_rn(v - bf2f(h));
      }
      const size_t bo = (((size_t)hby * 24 + ki) * 512 + c) * 8;
      *(us8*)(Bhi + bo) = hv;
      *(us8*)(Blo + bo) = lv;
    }
  } else {
    const int l = bx - 847;  // 0..511
    hist[l * 256 + t] = 0;
    if (l == 0 && t < NB) {
      bandcount[t] = 0;
      filtcount[t] = 0;
    }
  }
}

// ---------------- P/Q via split-bf16 MFMA ----------------
__global__ __launch_bounds__(256) void pq_mfma_kernel(
    const unsigned short* __restrict__ Ahi, const unsigned short* __restrict__ Alo,
    const unsigned short* __restrict__ Bhi, const unsigned short* __restrict__ Blo,
    float* __restrict__ P, float* __restrict__ Q) {
  __shared__ unsigned short AsmH[128 * 32], AsmL[128 * 32];
  const int tile = blockIdx.x;
  const int hby = blockIdx.y;
  const int tid = threadIdx.x;
  const int lane = tid & 63, w = tid >> 6;
  const int wm = w & 1, wn = w >> 1;
  const int lm = lane & 15, lq = lane >> 4;

  f32x4 acc[4][4];
#pragma unroll
  for (int i = 0; i < 4; ++i)
#pragma unroll
    for (int j = 0; j < 4; ++j) acc[i][j] = (f32x4){0.f, 0.f, 0.f, 0.f};

  const unsigned short* AbH = Ahi + (size_t)tile * 24 * 4096;
  const unsigned short* AbL = Alo + (size_t)tile * 24 * 4096;
  const unsigned short* BbH = Bhi + (size_t)hby * 24 * 4096;
  const unsigned short* BbL = Blo + (size_t)hby * 24 * 4096;
  const int a_off = (wm * 64 + lm) * 32 + (lq ^ ((lm >> 1) & 3)) * 8;
  const int b_off = (wn * 64 + lm) * 32 + lq * 8;

  for (int ki = 0; ki < 24; ++ki) {
    async_copy16(AbH + (size_t)ki * 4096 + tid * 8, AsmH + tid * 8);
    async_copy16(AbH + (size_t)ki * 4096 + (tid + 256) * 8, AsmH + (tid + 256) * 8);
    async_copy16(AbL + (size_t)ki * 4096 + tid * 8, AsmL + tid * 8);
    async_copy16(AbL + (size_t)ki * 4096 + (tid + 256) * 8, AsmL + (tid + 256) * 8);
    bf16x8 bh[4], bl[4];
#pragma unroll
    for (int ni = 0; ni < 4; ++ni) {
      bh[ni] = *reinterpret_cast<const bf16x8*>(BbH + (size_t)ki * 4096 + b_off + ni * 512);
      bl[ni] = *reinterpret_cast<const bf16x8*>(BbL + (size_t)ki * 4096 + b_off + ni * 512);
    }
    __syncthreads();
    bf16x8 ah[4], al[4];
#pragma unroll
    for (int mi = 0; mi < 4; ++mi) {
      ah[mi] = *reinterpret_cast<const bf16x8*>(AsmH + a_off + mi * 512);
      al[mi] = *reinterpret_cast<const bf16x8*>(AsmL + a_off + mi * 512);
    }
#pragma unroll
    for (int ni = 0; ni < 4; ++ni)
#pragma unroll
      for (int mi = 0; mi < 4; ++mi) {
        acc[mi][ni] = __builtin_amdgcn_mfma_f32_16x16x32_bf16(ah[mi], bh[ni], acc[mi][ni], 0, 0, 0);
        acc[mi][ni] = __builtin_amdgcn_mfma_f32_16x16x32_bf16(ah[mi], bl[ni], acc[mi][ni], 0, 0, 0);
        acc[mi][ni] = __builtin_amdgcn_mfma_f32_16x16x32_bf16(al[mi], bh[ni], acc[mi][ni], 0, 0, 0);
      }
    __syncthreads();
  }

  float* Obase = (hby < 6) ? P : Q;
  const int cb = ((hby < 6) ? hby : hby - 6) * 128 + wn * 64 + lm;
  const int rowb = tile * 128 + wm * 64 + lq * 4;
#pragma unroll
  for (int mi = 0; mi < 4; ++mi)
#pragma unroll
    for (int ni = 0; ni < 4; ++ni)
#pragma unroll
      for (int r = 0; r < 4; ++r)
        Obase[(size_t)(rowb + mi * 16 + r) * HH + cb + ni * 16] = acc[mi][ni][r];
}

// ---------------- MFMA scoring v7: LDS-windowed emb staging (coalesced) ----------------
__global__ __launch_bounds__(512, 4) void score_mfma7_kernel(
    const float* __restrict__ emb, const int* __restrict__ spans,
    const unsigned short* __restrict__ Bt, const float* __restrict__ w_s,
    const float* __restrict__ P, const float* __restrict__ Q, const float* __restrict__ R,
    float* __restrict__ spart, int S) {
  __shared__ unsigned short Asm[128 * 32];  // 8 KB
  __shared__ float ew[2][WCAP * 32];        // 2 x 5 KB emb window slices
  __shared__ int ssm[128], eem[128], wwm[128];
  __shared__ float sred[128 * 4];
  __shared__ int rminS, rmaxS;

  const int colblk = blockIdx.x;  // 0..2 (256-col block)
  const int tile = blockIdx.y;    // 0..236
  const int b = blockIdx.z;
  const int tid = threadIdx.x;
  const int lane = tid & 63, w = tid >> 6;  // 8 waves
  const int wm = w & 1, wn = w >> 1;
  const int lm = lane & 15, lq = lane >> 4;

  if (tid < 128) {
    int g = tile * 128 + tid;
    int gg = g < S ? g : S - 1;
    int s = spans[2 * gg], e = spans[2 * gg + 1];
    ssm[tid] = s; eem[tid] = e; wwm[tid] = e - s;
  }
  __syncthreads();
  if (tid == 0) {
    int rmn = ssm[0], rmx = eem[0];
    for (int i = 1; i < 128; ++i) {
      rmn = min(rmn, ssm[i]);
      rmx = max(rmx, eem[i]);
    }
    rminS = rmn; rmaxS = rmx;
  }
  __syncthreads();
  const int rmin = rminS;
  int W = rmaxS - rmin + 1;
  if (W > WCAP) W = WCAP;  // provably never triggers

  // staging: thread t < W*8 loads one float4 of the k-slice window (coalesced)
  const int sr = tid >> 3, sc = (tid & 7) * 4;
  const bool stager = (tid < W * 8);
  const float* gsrc = emb + ((size_t)b * NN + rmin + sr) * HH + sc;
  const int ewoff = sr * 32 + sc;

  // pack: thread handles row arow, k-octet kg (swizzled)
  const int arow = tid >> 2;
  const int kgs = tid & 3;
  const int kg = kgs ^ ((arow >> 1) & 3);
  const int xo = (ssm[arow] - rmin) * 32 + kg * 8;
  const int yo = (eem[arow] - rmin) * 32 + kg * 8;
  const int aw_off = (arow * 4 + kgs) * 8;

  f32x4 acc[4][4];
#pragma unroll
  for (int i = 0; i < 4; ++i)
#pragma unroll
    for (int j = 0; j < 4; ++j) acc[i][j] = (f32x4){0.f, 0.f, 0.f, 0.f};

  const int hby = colblk * 2 + (wn >> 1);
  const unsigned short* Bb = Bt + (size_t)hby * 24 * 4096;
  const int b_off = ((wn & 1) * 64 + lm) * 32 + lq * 8;
  const int a_off = (wm * 64 + lm) * 32 + (lq ^ ((lm >> 1) & 3)) * 8;

  float4 reg = make_float4(0.f, 0.f, 0.f, 0.f);
  if (stager) {
    float4 r0 = *(const float4*)gsrc;          // ki = 0 slice
    *(float4*)(&ew[0][ewoff]) = r0;
    reg = *(const float4*)(gsrc + 32);         // ki = 1 slice
  }
  __syncthreads();

  int cur = 0;
  for (int ki = 0; ki < 24; ++ki) {
    // pack bf16(x*y) from LDS window
    float4 x0 = *(const float4*)(&ew[cur][xo]);
    float4 x1 = *(const float4*)(&ew[cur][xo + 4]);
    float4 y0 = *(const float4*)(&ew[cur][yo]);
    float4 y1 = *(const float4*)(&ew[cur][yo + 4]);
    us8 v;
    v[0] = f2bf_rn(x0.x * y0.x); v[1] = f2bf_rn(x0.y * y0.y);
    v[2] = f2bf_rn(x0.z * y0.z); v[3] = f2bf_rn(x0.w * y0.w);
    v[4] = f2bf_rn(x1.x * y1.x); v[5] = f2bf_rn(x1.y * y1.y);
    v[6] = f2bf_rn(x1.z * y1.z); v[7] = f2bf_rn(x1.w * y1.w);
    *(us8*)(Asm + aw_off) = v;
    if (stager && ki < 23) *(float4*)(&ew[1 - cur][ewoff]) = reg;
    __syncthreads();  // Asm + next ew slice ready; ew[cur] reads complete
    if (stager && ki + 2 < 24)
      reg = *(const float4*)(gsrc + (size_t)(ki + 2) * 32);  // overlaps MFMA
    bf16x8 afr[4];
#pragma unroll
    for (int mi = 0; mi < 4; ++mi)
      afr[mi] = *reinterpret_cast<const bf16x8*>(Asm + a_off + mi * 512);
#pragma unroll
    for (int ni = 0; ni < 4; ++ni) {
      bf16x8 bfr = *reinterpret_cast<const bf16x8*>(Bb + (size_t)ki * 4096 + b_off + ni * 512);
#pragma unroll
      for (int mi = 0; mi < 4; ++mi)
        acc[mi][ni] = __builtin_amdgcn_mfma_f32_16x16x32_bf16(afr[mi], bfr, acc[mi][ni], 0, 0, 0);
    }
    __syncthreads();  // fragment reads done -> Asm writable next iter
    cur ^= 1;
  }

  const int cbase = colblk * 256 + wn * 64 + lm;
  float wsv[4];
#pragma unroll
  for (int ni = 0; ni < 4; ++ni) wsv[ni] = w_s[cbase + ni * 16];

#pragma unroll
  for (int mi = 0; mi < 4; ++mi) {
#pragma unroll
    for (int r = 0; r < 4; ++r) {
      const int rowl = wm * 64 + mi * 16 + lq * 4 + r;
      const int s = ssm[rowl], e = eem[rowl], wd = wwm[rowl];
      const float* Pp = P + ((size_t)b * NN + s) * HH + cbase;
      const float* Qp = Q + ((size_t)b * NN + e) * HH + cbase;
      const float* Rp = R + (size_t)wd * HH + cbase;
      float psum = 0.f;
#pragma unroll
      for (int ni = 0; ni < 4; ++ni) {
        float z = acc[mi][ni][r] + Pp[ni * 16] + Qp[ni * 16] + Rp[ni * 16];
        psum = fmaf(gelu_f(z), wsv[ni], psum);
      }
      psum += __shfl_xor(psum, 1);
      psum += __shfl_xor(psum, 2);
      psum += __shfl_xor(psum, 4);
      psum += __shfl_xor(psum, 8);
      if (lm == 0) sred[rowl * 4 + wn] = psum;
    }
  }
  __syncthreads();
  if (tid < 128) {
    int g = tile * 128 + tid;
    if (g < S)
      spart[(size_t)colblk * ((size_t)NB * S) + (size_t)b * S + g] =
          sred[tid * 4] + sred[tid * 4 + 1] + sred[tid * 4 + 2] + sred[tid * 4 + 3];
  }
}

// ---------------- fused combine + 16-bit histogram ----------------
__global__ void combine_hist_kernel(const float* __restrict__ sp, const int* __restrict__ spans,
                                    const float* __restrict__ b_s, const int* __restrict__ lengths,
                                    float* __restrict__ scores, unsigned* __restrict__ hist,
                                    int S) {
  int idx = blockIdx.x * 256 + threadIdx.x;
  if (idx >= NB * S) return;
  int b = idx / S, i = idx - b * S;
  size_t st = (size_t)NB * S;
  float v = b_s[0];
#pragma unroll
  for (int j = 0; j < 3; ++j) v += sp[j * st + idx];
  if (spans[2 * i + 1] >= lengths[b]) v += -1000000.0f;
  scores[idx] = v;
  unsigned key = f2key(v) >> 16;
  atomicAdd(&hist[(size_t)b * 65536 + key], 1u);
}

// ---------------- scan bins descending -> kth bin lower edge ----------------
__global__ __launch_bounds__(1024) void scan16_kernel(const unsigned* __restrict__ hist,
                                                      const int* __restrict__ kptr,
                                                      float* __restrict__ pivotf) {
  const int b = blockIdx.x;
  const unsigned* hb = hist + (size_t)b * 65536;
  const int tid = threadIdx.x;
  const unsigned k = (unsigned)kptr[0];
  __shared__ unsigned acc[1024];
  unsigned s = 0;
  for (int j = 0; j < 64; ++j) s += hb[tid * 64 + j];
  const unsigned mysum = s;
  acc[tid] = s;
  __syncthreads();
  for (int off = 1; off < 1024; off <<= 1) {
    unsigned v = (tid + off < 1024) ? acc[tid + off] : 0u;
    __syncthreads();
    acc[tid] += v;
    __syncthreads();
  }
  const unsigned above = acc[tid] - mysum;
  if (above < k && acc[tid] >= k) {
    unsigned cum = above;
    int binf = tid * 64;
    for (int j = 63; j >= 0; --j) {
      unsigned c = hb[tid * 64 + j];
      if (cum + c >= k) { binf = tid * 64 + j; break; }
      cum += c;
    }
    pivotf[b] = key2f(((unsigned)binf) << 16);
  }
}

// ---------------- band collect (approx scores near pivot) ----------------
__global__ void band_kernel(const float* __restrict__ scores, const float* __restrict__ pivotf,
                            int* __restrict__ bandcount, int* __restrict__ bandlist, int S) {
  int idx = blockIdx.x * 256 + threadIdx.x;
  if (idx >= NB * S) return;
  int b = idx / S, i = idx - b * S;
  if (fabsf(scores[idx] - pivotf[b]) <= BAND_TAU) {
    int slot = atomicAdd(&bandcount[b], 1);
    if (slot < BANDCAP) bandlist[b * BANDCAP + slot] = i;
  }
}

// ---------------- exact fp32 rescore of band spans ----------------
__global__ __launch_bounds__(256) void rescore_kernel(
    const float* __restrict__ emb, const int* __restrict__ spans,
    const float* __restrict__ W1, const float* __restrict__ w_s,
    const float* __restrict__ b_s, const int* __restrict__ lengths,
    const float* __restrict__ P, const float* __restrict__ Q, const float* __restrict__ R,
    const int* __restrict__ bandcount, const int* __restrict__ bandlist,
    float* __restrict__ scores, int S) {
  const int b = blockIdx.y;
  int cnt = bandcount[b];
  if (cnt > BANDCAP) cnt = BANDCAP;
  if ((int)blockIdx.x >= cnt) return;
  const int i = bandlist[b * BANDCAP + blockIdx.x];
  const int s = spans[2 * i], e = spans[2 * i + 1], wd = e - s;
  const int tid = threadIdx.x;
  __shared__ float prod[HH];
  __shared__ float red[256];
  for (int c = tid; c < HH; c += 256)
    prod[c] = emb[((size_t)b * NN + s) * HH + c] * emb[((size_t)b * NN + e) * HH + c];
  __syncthreads();
  const float* W1c = W1 + (size_t)(2 * HH) * HH;
  float psum = 0.f;
  for (int c0 = 0; c0 < HH; c0 += 256) {
    const int c = c0 + tid;
    float a = P[((size_t)b * NN + s) * HH + c] + Q[((size_t)b * NN + e) * HH + c] + R[(size_t)wd * HH + c];
    for (int k = 0; k < HH; ++k) a = fmaf(prod[k], W1c[(size_t)k * HH + c], a);
    psum = fmaf(gelu_f(a), w_s[c], psum);
  }
  red[tid] = psum;
  __syncthreads();
  for (int off = 128; off > 0; off >>= 1) {
    if (tid < off) red[tid] += red[tid + off];
    __syncthreads();
  }
  if (tid == 0) {
    float v = red[0] + b_s[0];
    if (e >= lengths[b]) v += -1000000.0f;
    scores[(size_t)b * S + i] = v;
  }
}

// ---------------- parallel candidate filter (final scores) ----------------
__global__ void filt_kernel(const float* __restrict__ scores, const float* __restrict__ pivotf,
                            int* __restrict__ filtcount, int* __restrict__ filtlist, int S) {
  int idx = blockIdx.x * 256 + threadIdx.x;
  if (idx >= NB * S) return;
  int b = idx / S, i = idx - b * S;
  if (scores[idx] > pivotf[b] - 0.01f) {
    int slot = atomicAdd(&filtcount[b], 1);
    if (slot < FILTCAP) filtlist[b * FILTCAP + slot] = i;
  }
}

// ---------------- exact top-k on candidate set ----------------
__global__ __launch_bounds__(1024) void sel_kernel(
    const float* __restrict__ scores, const int* __restrict__ spans,
    const int* __restrict__ kptr, const int* __restrict__ filtcount,
    const int* __restrict__ filtlist,
    float* __restrict__ out_spans, int* __restrict__ sel, int S) {
  const int b = blockIdx.x;
  const int tid = threadIdx.x;
  const int k = kptr[0];
  __shared__ unsigned keys[FILTCAP];
  __shared__ int idxs[FILTCAP];
  __shared__ unsigned hist[256];
  __shared__ unsigned sh_prefix;
  __shared__ int sh_remaining;
  __shared__ int selcnt;
  __shared__ int slist[512];

  int M = filtcount[b];
  if (M > FILTCAP) M = FILTCAP;
  for (int i = tid; i < M; i += 1024) {
    int gi = filtlist[b * FILTCAP + i];
    idxs[i] = gi;
    keys[i] = f2key(scores[(size_t)b * S + gi]);
  }
  if (tid == 0) selcnt = 0;
  __syncthreads();

  unsigned prefix = 0;
  int remaining = k;
  for (int round = 0; round < 4; ++round) {
    const int shift = 24 - 8 * round;
    if (tid < 256) hist[tid] = 0;
    __syncthreads();
    for (int i = tid; i < M; i += 1024) {
      unsigned key = keys[i];
      if (round == 0 || (key >> (shift + 8)) == prefix)
        atomicAdd(&hist[(key >> shift) & 255u], 1u);
    }
    __syncthreads();
    if (tid == 0) {
      int cum = 0;
      for (int bin = 255; bin >= 0; --bin) {
        int c = (int)hist[bin];
        if (cum + c >= remaining) {
          sh_prefix = (prefix << 8) | (unsigned)bin;
          sh_remaining = remaining - cum;
          break;
        }
        cum += c;
      }
    }
    __syncthreads();
    prefix = sh_prefix;
    remaining = sh_remaining;
    __syncthreads();
  }
  const unsigned pk = prefix;
  const int m_eq = remaining;

  for (int i = tid; i < M; i += 1024) {
    unsigned key = keys[i];
    bool pick = false;
    if (key > pk) {
      pick = true;
    } else if (key == pk) {
      int r = 0;
      const int myidx = idxs[i];
      for (int j = 0; j < M; ++j)
        if (keys[j] == pk && idxs[j] < myidx) ++r;
      pick = (r < m_eq);
    }
    if (pick) {
      int p = atomicAdd(&selcnt, 1);
      if (p < 512) slist[p] = idxs[i];
    }
  }
  __syncthreads();

  for (int i = tid; i < k; i += 1024) {
    const int my = slist[i];
    int r = 0;
    for (int j = 0; j < k; ++j) r += (slist[j] < my);
    sel[b * KTOP + r] = my;
    out_spans[(b * KTOP + r) * 2 + 0] = (float)spans[2 * my];
    out_spans[(b * KTOP + r) * 2 + 1] = (float)spans[2 * my + 1];
  }
}

// ---------------- prep gather A: hi/lo bf16(x*y) for selected spans ----------------
__global__ __launch_bounds__(256) void prep_ga_kernel(
    const float* __restrict__ emb, const int* __restrict__ spans,
    const int* __restrict__ sel, unsigned short* __restrict__ GAhi,
    unsigned short* __restrict__ GAlo) {
  const int bx = blockIdx.x;     // 0..95: tile*24 + ki
  const int tile = bx / 24, ki = bx - tile * 24;
  const int b = blockIdx.y;
  const int t = threadIdx.x;
#pragma unroll
  for (int half = 0; half < 2; ++half) {
    const int c = t + half * 256;
    const int row = c >> 2, kgs = c & 3;
    const int kg = kgs ^ ((row >> 1) & 3);
    int j = tile * 128 + row;
    if (j >= KTOP) j = KTOP - 1;
    const int i = sel[b * KTOP + j];
    const int s = spans[2 * i], e = spans[2 * i + 1];
    const float* xr = emb + ((size_t)b * NN + s) * HH;
    const float* yr = emb + ((size_t)b * NN + e) * HH;
    const int k0 = ki * 32 + kg * 8;
    float4 x0 = *(const float4*)(xr + k0);
    float4 x1 = *(const float4*)(xr + k0 + 4);
    float4 y0 = *(const float4*)(yr + k0);
    float4 y1 = *(const float4*)(yr + k0 + 4);
    const float pv[8] = {x0.x * y0.x, x0.y * y0.y, x0.z * y0.z, x0.w * y0.w,
                         x1.x * y1.x, x1.y * y1.y, x1.z * y1.z, x1.w * y1.w};
    us8 hv, lv;
#pragma unroll
    for (int q = 0; q < 8; ++q) {
      unsigned short h = f2bf_rn(pv[q]);
      hv[q] = h;
      lv[q] = f2bf_rn(pv[q] - bf2f(h));
    }
    const size_t base = (((size_t)(b * 4 + tile) * 24 + ki) * 512 + c) * 8;
    *(us8*)(GAhi + base) = hv;
    *(us8*)(GAlo + base) = lv;
  }
}

// ---------------- gather via split-bf16 MFMA: h embeddings + score partials ----------------
__global__ __launch_bounds__(256) void gather_mfma_kernel(
    const int* __restrict__ spans, const int* __restrict__ sel,
    const unsigned short* __restrict__ GAhi, const unsigned short* __restrict__ GAlo,
    const unsigned short* __restrict__ Bt, const unsigned short* __restrict__ Btlo,
    const float* __restrict__ w_s,
    const float* __restrict__ P, const float* __restrict__ Q, const float* __restrict__ R,
    float* __restrict__ outh, float* __restrict__ spartg) {
  __shared__ unsigned short AsmH[128 * 32], AsmL[128 * 32];
  __shared__ int ssm[128], eem[128], wwm[128], vvm[128];
  __shared__ float sred[128 * 2];
  const int tile = blockIdx.x;  // 0..3
  const int hby = blockIdx.y;   // 0..5
  const int b = blockIdx.z;
  const int tid = threadIdx.x;
  const int lane = tid & 63, w = tid >> 6;
  const int wm = w & 1, wn = w >> 1;
  const int lm = lane & 15, lq = lane >> 4;

  if (tid < 128) {
    int j = tile * 128 + tid;
    int valid = (j < KTOP) ? 1 : 0;
    int jj = valid ? j : KTOP - 1;
    int i = sel[b * KTOP + jj];
    ssm[tid] = spans[2 * i];
    eem[tid] = spans[2 * i + 1];
    wwm[tid] = eem[tid] - ssm[tid];
    vvm[tid] = valid;
  }

  f32x4 acc[4][4];
#pragma unroll
  for (int i = 0; i < 4; ++i)
#pragma unroll
    for (int j = 0; j < 4; ++j) acc[i][j] = (f32x4){0.f, 0.f, 0.f, 0.f};

  const unsigned short* AbH = GAhi + (size_t)(b * 4 + tile) * 24 * 4096;
  const unsigned short* AbL = GAlo + (size_t)(b * 4 + tile) * 24 * 4096;
  const unsigned short* BbH = Bt + (size_t)hby * 24 * 4096;
  const unsigned short* BbL = Btlo + (size_t)hby * 24 * 4096;
  const int a_off = (wm * 64 + lm) * 32 + (lq ^ ((lm >> 1) & 3)) * 8;
  const int b_off = (wn * 64 + lm) * 32 + lq * 8;

  for (int ki = 0; ki < 24; ++ki) {
    async_copy16(AbH + (size_t)ki * 4096 + tid * 8, AsmH + tid * 8);
    async_copy16(AbH + (size_t)ki * 4096 + (tid + 256) * 8, AsmH + (tid + 256) * 8);
    async_copy16(AbL + (size_t)ki * 4096 + tid * 8, AsmL + tid * 8);
    async_copy16(AbL + (size_t)ki * 4096 + (tid + 256) * 8, AsmL + (tid + 256) * 8);
    bf16x8 bh[4], bl[4];
#pragma unroll
    for (int ni = 0; ni < 4; ++ni) {
      bh[ni] = *reinterpret_cast<const bf16x8*>(BbH + (size_t)ki * 4096 + b_off + ni * 512);
      bl[ni] = *reinterpret_cast<const bf16x8*>(BbL + (size_t)ki * 4096 + b_off + ni * 512);
    }
    __syncthreads();
    bf16x8 ah[4], al[4];
#pragma unroll
    for (int mi = 0; mi < 4; ++mi) {
      ah[mi] = *reinterpret_cast<const bf16x8*>(AsmH + a_off + mi * 512);
      al[mi] = *reinterpret_cast<const bf16x8*>(AsmL + a_off + mi * 512);
    }
#pragma unroll
    for (int ni = 0; ni < 4; ++ni)
#pragma unroll
      for (int mi = 0; mi < 4; ++mi) {
        acc[mi][ni] = __builtin_amdgcn_mfma_f32_16x16x32_bf16(ah[mi], bh[ni], acc[mi][ni], 0, 0, 0);
        acc[mi][ni] = __builtin_amdgcn_mfma_f32_16x16x32_bf16(ah[mi], bl[ni], acc[mi][ni], 0, 0, 0);
        acc[mi][ni] = __builtin_amdgcn_mfma_f32_16x16x32_bf16(al[mi], bh[ni], acc[mi][ni], 0, 0, 0);
      }
    __syncthreads();
  }

  const int hbg = hby * 128;
  float wsv[4];
#pragma unroll
  for (int ni = 0; ni < 4; ++ni) wsv[ni] = w_s[hbg + wn * 64 + ni * 16 + lm];

#pragma unroll
  for (int mi = 0; mi < 4; ++mi) {
#pragma unroll
    for (int r = 0; r < 4; ++r) {
      const int rowl = wm * 64 + mi * 16 + lq * 4 + r;
      const int s = ssm[rowl], e = eem[rowl], wd = wwm[rowl];
      const float* Pp = P + ((size_t)b * NN + s) * HH + hbg + wn * 64 + lm;
      const float* Qp = Q + ((size_t)b * NN + e) * HH + hbg + wn * 64 + lm;
      const float* Rp = R + (size_t)wd * HH + hbg + wn * 64 + lm;
      float psum = 0.f;
      const int j = tile * 128 + rowl;
      float* op = outh + (size_t)(b * KTOP + j) * HH + hbg + wn * 64 + lm;
#pragma unroll
      for (int ni = 0; ni < 4; ++ni) {
        float z = acc[mi][ni][r] + Pp[ni * 16] + Qp[ni * 16] + Rp[ni * 16];
        float gl = gelu_f(z);
        if (vvm[rowl]) op[ni * 16] = gl;
        psum = fmaf(gl, wsv[ni], psum);
      }
      psum += __shfl_xor(psum, 1);
      psum += __shfl_xor(psum, 2);
      psum += __shfl_xor(psum, 4);
      psum += __shfl_xor(psum, 8);
      if (lm == 0) sred[rowl * 2 + wn] = psum;
    }
  }
  __syncthreads();
  if (tid < 128)
    spartg[(size_t)hby * (NB * GROWS) + b * GROWS + tile * 128 + tid] =
        sred[tid * 2] + sred[tid * 2 + 1];
}

// ---------------- final scores for selected spans ----------------
__global__ void score_fin_kernel(const float* __restrict__ spartg, const int* __restrict__ sel,
                                 const int* __restrict__ spans, const float* __restrict__ b_s,
                                 const int* __restrict__ lengths, float* __restrict__ out_scores) {
  int idx = blockIdx.x * 256 + threadIdx.x;
  if (idx >= NB * KTOP) return;
  int b = idx / KTOP, j = idx - b * KTOP;
  float v = b_s[0];
#pragma unroll
  for (int hby = 0; hby < 6; ++hby)
    v += spartg[(size_t)hby * (NB * GROWS) + b * GROWS + j];
  int i = sel[idx];
  if (spans[2 * i + 1] >= lengths[b]) v += -1000000.0f;
  out_scores[idx] = v;
}

extern "C" void kernel_launch(void* const* d_in, const int* in_sizes, int n_in,
                              void* d_out, int out_size, void* d_ws, size_t ws_size,
                              hipStream_t stream) {
  const float* emb = (const float*)d_in[0];
  const int* mask = (const int*)d_in[1];
  const int* spans = (const int*)d_in[2];
  const float* wemb = (const float*)d_in[3];
  const float* W1 = (const float*)d_in[4];
  const float* b1 = (const float*)d_in[5];
  const float* w_s = (const float*)d_in[6];
  const float* b_s = (const float*)d_in[7];
  const int* kptr = (const int*)d_in[8];
  const int S = in_sizes[2] / 2;  // 30285
  float* out = (float*)d_out;

  char* wp = (char*)d_ws;
  auto take = [&](size_t bytes) {
    char* p = wp;
    wp += (bytes + 63) & ~(size_t)63;
    return p;
  };
  float* Pb = (float*)take((size_t)NB * NN * HH * 4);
  float* Qb = (float*)take((size_t)NB * NN * HH * 4);
  float* Rb = (float*)take((size_t)MAXW * HH * 4);
  float* spart = (float*)take(3 * (size_t)NB * S * 4);
  float* scoresb = (float*)take((size_t)NB * S * 4);
  float* spartg = (float*)take(6 * (size_t)NB * GROWS * 4);
  float* pivotf = (float*)take(NB * 4);
  unsigned short* AimgHi = (unsigned short*)take((size_t)16 * 24 * 4096 * 2);
  unsigned short* AimgLo = (unsigned short*)take((size_t)16 * 24 * 4096 * 2);
  unsigned short* BimgHi = (unsigned short*)take((size_t)12 * 24 * 4096 * 2);
  unsigned short* BimgLo = (unsigned short*)take((size_t)12 * 24 * 4096 * 2);
  unsigned short* Bt = (unsigned short*)take((size_t)6 * 24 * 4096 * 2);
  unsigned short* Btlo = (unsigned short*)take((size_t)6 * 24 * 4096 * 2);
  unsigned short* GAhi = (unsigned short*)take((size_t)NB * 4 * 24 * 4096 * 2);
  unsigned short* GAlo = (unsigned short*)take((size_t)NB * 4 * 24 * 4096 * 2);
  unsigned* hist16b = (unsigned*)take((size_t)NB * 65536 * 4);
  int* selb = (int*)take(NB * KTOP * 4);
  int* lengthsb = (int*)take(NB * 4);
  int* bandcount = (int*)take(NB * 4);
  int* bandlist = (int*)take((size_t)NB * BANDCAP * 4);
  int* filtcount = (int*)take(NB * 4);
  int* filtlist = (int*)take((size_t)NB * FILTCAP * 4);

  const size_t OFF1 = (size_t)NB * KTOP * HH;    // embs
  const size_t OFF2 = OFF1 + (size_t)NB * KTOP;  // scores | spans

  const int tiles = (S + 127) / 128;  // 237

  prep_all_kernel<<<dim3(1359), dim3(256), 0, stream>>>(
      mask, lengthsb, wemb, W1, b1, Rb, Bt, Btlo, emb, AimgHi, AimgLo, BimgHi, BimgLo,
      hist16b, bandcount, filtcount);
  pq_mfma_kernel<<<dim3(16, 12), dim3(256), 0, stream>>>(AimgHi, AimgLo, BimgHi, BimgLo, Pb, Qb);
  score_mfma7_kernel<<<dim3(3, tiles, NB), dim3(512), 0, stream>>>(
      emb, spans, Bt, w_s, Pb, Qb, Rb, spart, S);
  combine_hist_kernel<<<dim3((NB * S + 255) / 256), dim3(256), 0, stream>>>(
      spart, spans, b_s, lengthsb, scoresb, hist16b, S);
  scan16_kernel<<<dim3(NB), dim3(1024), 0, stream>>>(hist16b, kptr, pivotf);
  band_kernel<<<dim3((NB * S + 255) / 256), dim3(256), 0, stream>>>(
      scoresb, pivotf, bandcount, bandlist, S);
  rescore_kernel<<<dim3(BANDCAP, NB), dim3(256), 0, stream>>>(
      emb, spans, W1, w_s, b_s, lengthsb, Pb, Qb, Rb, bandcount, bandlist, scoresb, S);
  filt_kernel<<<dim3((NB * S + 255) / 256), dim3(256), 0, stream>>>(
      scoresb, pivotf, filtcount, filtlist, S);
  sel_kernel<<<dim3(NB), dim3(1024), 0, stream>>>(
      scoresb, spans, kptr, filtcount, filtlist, out + OFF2, selb, S);
  prep_ga_kernel<<<dim3(96, NB), dim3(256), 0, stream>>>(emb, spans, selb, GAhi, GAlo);
  gather_mfma_kernel<<<dim3(4, 6, NB), dim3(256), 0, stream>>>(
      spans, selb, GAhi, GAlo, Bt, Btlo, w_s, Pb, Qb, Rb, out, spartg);
  score_fin_kernel<<<dim3((NB * KTOP + 255) / 256), dim3(256), 0, stream>>>(
      spartg, selb, spans, b_s, lengthsb, out + OFF1);
}